// Round 15
// baseline (155.465 us; speedup 1.0000x reference)
//
#include <hip/hip_runtime.h>
#include <hip/hip_fp16.h>

#define B_   8
#define CIN  256
#define T_   4096
#define TP   4097    // padded T (row 0 = zeros, row t+1 = x[t])
#define CO   256
#define O4   1024
#define NN   32768   // B_*T_
#define NCH  128     // chunks along T
#define CL   32      // chunk length

// ws layout (float offsets) — f16 single-precision pipeline (70 MB total)
#define OFF_XF   0            // half [8][4097][256]
#define OFF_WF   4195328      // half [1024][512]
#define OFF_F16  4457472      // half [8][4096][256]
#define OFF_IZ16 8651776
#define OFF_O16  12846080
#define OFF_A    17040384     // float [8][128][256]
#define OFF_B    17302528

typedef __attribute__((ext_vector_type(8))) _Float16 half8;
typedef __attribute__((ext_vector_type(4))) float floatx4;

__device__ __forceinline__ float fsig(float x)  { return 1.0f / (1.0f + __expf(-x)); }
__device__ __forceinline__ float ftanh(float x) { return 2.0f / (1.0f + __expf(-2.0f * x)) - 1.0f; }

__device__ __forceinline__ unsigned short f16b(float v) {
    return __half_as_ushort(__float2half(v));
}

// async 16B/lane global->LDS DMA; lds base must be wave-uniform (dest = base + lane*16)
__device__ __forceinline__ void glds16(const unsigned short* g, unsigned short* l) {
    __builtin_amdgcn_global_load_lds(
        (const __attribute__((address_space(1))) unsigned*)g,
        (__attribute__((address_space(3))) unsigned*)l, 16, 0, 0);
}

// merged converts: bid<2048 -> W repack to f16; bid>=2048 -> X transpose to f16.
// W[o=g*256+c][i][j] -> Wf[r=c*4+g][k=j*256+i].  x[b][c][t] -> Xf[b][t+1][c].
__global__ void convert_kernel(const float* __restrict__ W,
                               const float* __restrict__ x,
                               unsigned short* __restrict__ Wf,
                               unsigned short* __restrict__ Xf) {
    __shared__ float tile[64][69];      // 69 mod 32 = 5 -> conflict-free both phases
    const int bid = blockIdx.x;
    const int tid = threadIdx.x;
    if (bid < 2048) {
        int e = bid * 256 + tid;        // 1024*512 elements
        int r = e >> 9, k = e & 511;
        int g = r & 3, c = r >> 2;
        int j = k >> 8, i = k & 255;
        float v = W[((size_t)((g << 8) + c)) * 512 + i * 2 + j];
        Wf[e] = f16b(v);
        return;
    }
    const int b2 = bid - 2048;
    const int t0 = (b2 & 63) * 64;
    const int c0 = ((b2 >> 6) & 3) * 64;
    const int b  = b2 >> 8;

    {   // read: float4 along t, 16 rows per pass
        int j4 = (tid & 15) * 4, r16 = tid >> 4;
#pragma unroll
        for (int p = 0; p < 4; p++) {
            int i = p * 16 + r16;
            float4 v = *(const float4*)&x[((size_t)(b * 256 + c0 + i)) * T_ + t0 + j4];
            tile[i][j4] = v.x; tile[i][j4 + 1] = v.y;
            tile[i][j4 + 2] = v.z; tile[i][j4 + 3] = v.w;
        }
    }
    if (t0 == 0 && tid < 64) {   // zero pad row (x[-1] = 0)
        Xf[(size_t)b * TP * 256 + c0 + tid] = 0;
    }
    __syncthreads();
    {   // write: 4 consecutive channels per thread, packed uint2 (8B) stores
        const int cslot = tid & 15, trow = tid >> 4;
#pragma unroll
        for (int p = 0; p < 4; p++) {
            int t = p * 16 + trow;
            unsigned lo = (unsigned)f16b(tile[cslot * 4 + 0][t])
                        | ((unsigned)f16b(tile[cslot * 4 + 1][t]) << 16);
            unsigned hi = (unsigned)f16b(tile[cslot * 4 + 2][t])
                        | ((unsigned)f16b(tile[cslot * 4 + 3][t]) << 16);
            size_t idx = ((size_t)b * TP + t0 + t + 1) * 256 + c0 + cslot * 4;
            uint2 pk; pk.x = lo; pk.y = hi;
            *(uint2*)&Xf[idx] = pk;
        }
    }
}

// C[r=1024][n=32768] = Wf · Xf^T, single-product f16 MFMA.
// Round 15 gemm = Round 13 verbatim (55.8us proven; R14's 64x64 wave tiles
// were null). 128x128 tile, 8 waves (2Mx4N, 64x32), BK=32, 16 K-steps,
// TRIPLE-buffered LDS (3 x 16KB = 48KB -> 3 blocks/CU, 24 waves/CU).
// Prefetch distance 2; per step: issue pair->buf[(i+2)%3], read frags from
// buf[i%3], lgkm+MFMA, vmcnt(2) [(i+1) pair landed], ONE barrier. Overwrite
// target (i+2)%3 == (i-1)%3, readers done before barrier i-1 => safe.
// XOR swizzle both sides (R7-proven). Grid map = R7 (FETCH 12.4MB measured).
// Buf d (ushort idx): A at d*8192, B at d*8192+4096.
__launch_bounds__(512, 6)
__global__ void gemm_mfma_kernel(const unsigned short* __restrict__ Xf,
                                 const unsigned short* __restrict__ Wf,
                                 const float* __restrict__ bias,
                                 __half* __restrict__ fw,
                                 __half* __restrict__ izw,
                                 __half* __restrict__ ow,
                                 float* __restrict__ Aw,
                                 float* __restrict__ Bw)
{
    __shared__ unsigned short smem_us[24576];   // 48 KiB

    const int tid  = threadIdx.x;
    const int wave = tid >> 6, lane = tid & 63;
    const int q = lane >> 4, mr = lane & 15;
    const int wm = wave >> 2, wn = wave & 3;     // 2 x 4 wave grid (M x N)

    // grid: 2048 = 8 xcd x (32 n-tiles x 8 r, r fastest -> X-tile L2-resident)
    const int bid   = blockIdx.x;
    const int xcd   = bid & 7;
    const int idx   = bid >> 3;                  // 0..255
    const int n_blk = xcd * 32 + (idx >> 3);     // 0..255
    const int r_blk = idx & 7;                   // 0..7
    const int r0 = r_blk * 128;
    const int n0 = n_blk * 128;
    const int bb = n0 >> 12;
    const int t0 = n0 & (T_ - 1);

    // staging: wave w stages rows w*16..w*16+15 of A and B; 1 DMA per plane.
    // XOR-swizzled source slice (within the row's contiguous 64B K-window).
    const int lrow = lane >> 2;                              // 0..15
    const int lcol = (((lane & 3) ^ ((lrow >> 1) & 3)) * 8); // swizzled ushort offset
    const unsigned short* pW = Wf + (size_t)(r0 + wave * 16 + lrow) * 512 + lcol;
    const unsigned short* pX = Xf + ((size_t)bb * TP + t0 + wave * 16 + lrow) * 256 + lcol;

    // fragment read bases (ushort offsets within one plane, swizzled slice)
    const int swz = (q ^ ((mr >> 1) & 3)) * 8;
    const int aoffb = (wm * 64 + mr) * 32 + swz;   // + v*512, v=0..3
    const int boffb = (wn * 32 + mr) * 32 + swz;   // + u*512, u=0..1
    const int wst = wave * 512;                  // wave staging offset in plane

    floatx4 acc[4][2];
#pragma unroll
    for (int v = 0; v < 4; v++)
#pragma unroll
        for (int u = 0; u < 2; u++) acc[v][u] = (floatx4){0.f, 0.f, 0.f, 0.f};

    // prologue: k0 -> buf0, k1 -> buf1 (pairs in FIFO order A,B)
    glds16(pW,      smem_us + wst);
    glds16(pX,      smem_us + 4096 + wst);
    glds16(pW + 32, smem_us + 8192 + wst);
    glds16(pX + 32, smem_us + 8192 + 4096 + wst);
    asm volatile("s_waitcnt vmcnt(2)" ::: "memory");   // k0 pair landed
    __builtin_amdgcn_s_barrier();
    __builtin_amdgcn_sched_barrier(0);

#pragma unroll 16
    for (int i = 0; i < 16; ++i) {
        const unsigned short* Ac = smem_us + (i % 3) * 8192;
        const unsigned short* Bc = Ac + 4096;
        unsigned short* dA = smem_us + ((i + 2) % 3) * 8192 + wst;
        unsigned short* dB = dA + 4096;
        const unsigned kkn = (unsigned)(((i + 2) & 15) * 32);  // wrap keeps counts uniform

        // issue next+1 pair early (lands under the next two MFMA phases)
        glds16(pW + kkn, dA);
        glds16(pX + kkn, dB);

        half8 ah[4], bh[2];
#pragma unroll
        for (int v = 0; v < 4; ++v) ah[v] = *(const half8*)(Ac + aoffb + v * 512);
#pragma unroll
        for (int u = 0; u < 2; ++u) bh[u] = *(const half8*)(Bc + boffb + u * 512);
        asm volatile("s_waitcnt lgkmcnt(0)" ::: "memory");
        __builtin_amdgcn_sched_barrier(0);
        __builtin_amdgcn_s_setprio(1);
#pragma unroll
        for (int v = 0; v < 4; ++v)
#pragma unroll
            for (int u = 0; u < 2; ++u)
                acc[v][u] = __builtin_amdgcn_mfma_f32_16x16x32_f16(ah[v], bh[u], acc[v][u], 0, 0, 0);
        __builtin_amdgcn_s_setprio(0);
        asm volatile("s_waitcnt vmcnt(2)" ::: "memory");   // (i+1) pair landed
        __builtin_amdgcn_s_barrier();
        __builtin_amdgcn_sched_barrier(0);
    }

    // ---------- epilogue ----------
    asm volatile("s_waitcnt vmcnt(0)" ::: "memory");   // drain wrap-staging junk DMAs
    __syncthreads();                     // LDS reused below
    __half* epf = (__half*)smem_us;      // [128][36] f16, 72B rows (conflict-free t-phase)
    __half* epz = epf + 128 * 36;
    __half* epo = epz + 128 * 36;        // total 27,648 B < 48 KiB
    const int ch_base = r0 >> 2;         // 32 channels per block

#pragma unroll
    for (int v = 0; v < 4; ++v) {
        const int cl = wm * 16 + v * 4 + q;          // local channel 0..31
        const int ch = ch_base + cl;
        const float bz  = bias[ch];
        const float bf_ = bias[256 + ch];
        const float bo  = bias[512 + ch];
        const float bi  = bias[768 + ch];
#pragma unroll
        for (int u = 0; u < 2; ++u) {
            const int t_l = wn * 32 + u * 16 + mr;   // local t 0..127
            float zv = ftanh(acc[v][u][0] + bz);
            float fv = fsig(acc[v][u][1] + bf_);
            float ov = fsig(acc[v][u][2] + bo);
            float iv = fsig(acc[v][u][3] + bi);
            const int off = t_l * 36 + cl;
            epf[off] = __float2half(fv);             // same f16 rounding as before
            epz[off] = __float2half(iv * zv);
            epo[off] = __float2half(ov);
        }
    }
    __syncthreads();

    // coalesced f16 stores: 4 threads per t-row, 8 channels (16B) each
    {
        const int t_r = tid >> 2;                    // 0..127
        const int c8 = (tid & 3) << 3;               // 0,8,16,24
        const size_t gbase = ((size_t)bb * T_ + t0 + t_r) * 256 + ch_base + c8;
        const int lb = t_r * 36 + c8;                // 8B-aligned
        union { uint2 u2[2]; uint4 u4; } pk;
        pk.u2[0] = *(const uint2*)&epf[lb];
        pk.u2[1] = *(const uint2*)&epf[lb + 4];
        *(uint4*)&fw[gbase] = pk.u4;
        pk.u2[0] = *(const uint2*)&epz[lb];
        pk.u2[1] = *(const uint2*)&epz[lb + 4];
        *(uint4*)&izw[gbase] = pk.u4;
        pk.u2[0] = *(const uint2*)&epo[lb];
        pk.u2[1] = *(const uint2*)&epo[lb + 4];
        *(uint4*)&ow[gbase] = pk.u4;
    }

    // fused scan phase 1: per-chunk (A = prod f, B = affine end); 4 chunks x 32 ch
    if (tid < 128) {
        const int chunk = tid >> 5;                  // 0..3
        const int c = tid & 31;
        float A = 1.0f, Bv = 0.0f;
        const int base = (chunk * 32) * 36 + c;
#pragma unroll 4
        for (int j = 0; j < 32; ++j) {
            float f  = __half2float(epf[base + j * 36]);
            float iz = __half2float(epz[base + j * 36]);
            Bv = fmaf(f, Bv, iz);
            A *= f;
        }
        const int chunk_abs = (t0 >> 5) + chunk;
        const size_t aidx = ((size_t)bb * NCH + chunk_abs) * 256 + ch_base + c;
        Aw[aidx] = A;
        Bw[aidx] = Bv;
    }
}

// Phase 3 v2: each block handles TWO consecutive chunks (grid 64 x 8 = 512
// blocks): computes its carry once (halved redundant carry work vs 1024
// blocks), then scans 64 t with the carry flowing across the chunk boundary
// for free; per-chunk hbuf transpose + float4 out stores (proven structure).
__global__ void scan_phase3(const __half* __restrict__ fw, const __half* __restrict__ izw,
                            const __half* __restrict__ ow,
                            const float* __restrict__ Aw, const float* __restrict__ Bw,
                            float* __restrict__ out)
{
    __shared__ float hbuf[CL][257];
    __shared__ float carry_s[256];
    int b = blockIdx.y, chx = blockIdx.x;
    int ch0 = chx * 2;                               // first of 2 chunks
    int tid = threadIdx.x;

    {   // carry over chunks 0..ch0-1 for channel tid (exclusive scan, batched)
        const int c = tid;
        float carry = 0.0f;
        for (int g = 0; g < 8; ++g) {
            if (g * 16 >= ch0) break;
            float Ar[16], Br[16];
#pragma unroll
            for (int j = 0; j < 16; ++j) {
                int jj = g * 16 + j;
                bool ok = jj < ch0;
                size_t idx2 = ((size_t)(b * NCH + (ok ? jj : 0))) * CO + c;
                Ar[j] = ok ? Aw[idx2] : 1.0f;
                Br[j] = ok ? Bw[idx2] : 0.0f;
            }
#pragma unroll
            for (int j = 0; j < 16; ++j) carry = fmaf(Ar[j], carry, Br[j]);
        }
        carry_s[c] = carry;
    }
    __syncthreads();

    float cs0 = 0.f, cs1 = 0.f;
    if (tid < 128) {
        cs0 = carry_s[tid * 2];
        cs1 = carry_s[tid * 2 + 1];
    }

    for (int sub = 0; sub < 2; ++sub) {
        const int ch = ch0 + sub;
        if (tid < 128) {
            const int c2 = tid * 2;
            size_t base = ((size_t)(b * T_ + ch * CL)) * CO + c2;
#pragma unroll 4
            for (int tt = 0; tt < CL; tt++) {
                __half2 f2  = *(const __half2*)&fw [base + (size_t)tt * CO];
                __half2 iz2 = *(const __half2*)&izw[base + (size_t)tt * CO];
                __half2 o2  = *(const __half2*)&ow [base + (size_t)tt * CO];
                float2 f  = __half22float2(f2);
                float2 iz = __half22float2(iz2);
                float2 o  = __half22float2(o2);
                cs0 = fmaf(f.x, cs0, iz.x);
                cs1 = fmaf(f.y, cs1, iz.y);
                hbuf[tt][c2]     = o.x * cs0;
                hbuf[tt][c2 + 1] = o.y * cs1;
            }
        }
        __syncthreads();

        // float4 out-stores: thread (tt-group, cc) writes 4 consecutive t
        {
            const int tt4 = (tid & 7) * 4;               // 0,4,...,28
            const int cc0 = tid >> 3;                    // 0..31
#pragma unroll
            for (int w = 0; w < 8; ++w) {
                const int cc = cc0 + w * 32;
                float4 h4;
                h4.x = hbuf[tt4 + 0][cc];
                h4.y = hbuf[tt4 + 1][cc];
                h4.z = hbuf[tt4 + 2][cc];
                h4.w = hbuf[tt4 + 3][cc];
                *(float4*)&out[((size_t)(b * CO + cc)) * T_ + ch * CL + tt4] = h4;
            }
        }
        __syncthreads();
    }
}

extern "C" void kernel_launch(void* const* d_in, const int* in_sizes, int n_in,
                              void* d_out, int out_size, void* d_ws, size_t ws_size,
                              hipStream_t stream) {
    const float* x    = (const float*)d_in[0];
    const float* W    = (const float*)d_in[1];
    const float* bias = (const float*)d_in[2];
    float* out = (float*)d_out;
    float* ws  = (float*)d_ws;

    unsigned short* Xf = (unsigned short*)(ws + OFF_XF);
    unsigned short* Wf = (unsigned short*)(ws + OFF_WF);
    __half* fw  = (__half*)(ws + OFF_F16);
    __half* izw = (__half*)(ws + OFF_IZ16);
    __half* ow  = (__half*)(ws + OFF_O16);
    float* Aw  = ws + OFF_A;
    float* Bw  = ws + OFF_B;

    convert_kernel<<<4096, 256, 0, stream>>>(W, x, Wf, Xf);
    gemm_mfma_kernel<<<(NN / 128) * (O4 / 128), 512, 0, stream>>>(
        Xf, Wf, bias, fw, izw, ow, Aw, Bw);
    scan_phase3<<<dim3(NCH / 2, B_), CO, 0, stream>>>(fw, izw, ow, Aw, Bw, out);
}